// Round 1
// baseline (1070.730 us; speedup 1.0000x reference)
//
#include <hip/hip_runtime.h>
#include <hip/hip_bf16.h>
#include <math.h>

// ---------------- helpers ----------------
__device__ __forceinline__ float wave_max64(float v) {
#pragma unroll
  for (int o = 32; o > 0; o >>= 1) v = fmaxf(v, __shfl_xor(v, o));
  return v;
}
__device__ __forceinline__ float wave_sum64(float v) {
#pragma unroll
  for (int o = 32; o > 0; o >>= 1) v += __shfl_xor(v, o);
  return v;
}
__device__ __forceinline__ float lrelu02(float v) { return v > 0.f ? v : 0.2f * v; }

// ---------------- CSR build ----------------
__global__ void hist_kernel(const int* __restrict__ dst, int* __restrict__ counts, int E) {
  int e = blockIdx.x * blockDim.x + threadIdx.x;
  if (e < E) atomicAdd(&counts[dst[e]], 1);
}

__global__ __launch_bounds__(1024) void scan_kernel(const int* __restrict__ counts,
                                                    int* __restrict__ offs, int n) {
  __shared__ int buf[1024];
  int tid = threadIdx.x;
  int running = 0;
  for (int base = 0; base < n; base += 1024) {
    int i = base + tid;
    int v = (i < n) ? counts[i] : 0;
    buf[tid] = v;
    __syncthreads();
    int x = v;
#pragma unroll
    for (int off = 1; off < 1024; off <<= 1) {
      int y = (tid >= off) ? buf[tid - off] : 0;
      __syncthreads();
      x += y;
      buf[tid] = x;
      __syncthreads();
    }
    if (i < n) offs[i] = running + x - v;  // exclusive
    running += buf[1023];
    __syncthreads();
  }
  if (tid == 0) offs[n] = running;
}

__global__ void scatter_kernel(const int* __restrict__ dst, const int* __restrict__ offs,
                               int* __restrict__ cursor, int* __restrict__ eidx, int E) {
  int e = blockIdx.x * blockDim.x + threadIdx.x;
  if (e < E) {
    int d = dst[e];
    int pos = offs[d] + atomicAdd(&cursor[d], 1);
    eidx[pos] = e;
  }
}

// ---------------- GEMM1: hs1 = x[n_id1] @ W1  (M x 602 @ 602 x 64) ----------------
__global__ __launch_bounds__(256) void gemm1_kernel(const float* __restrict__ x,
                                                    const int* __restrict__ n_id,
                                                    const float* __restrict__ W,
                                                    float* __restrict__ out, int M) {
  constexpr int K = 602, BK = 32;
  __shared__ float As[64][BK + 1];
  __shared__ float Bs[BK][64];
  __shared__ int rows[64];
  int tid = threadIdx.x;
  int rbase = blockIdx.x * 64;
  if (tid < 64) {
    int r = rbase + tid;
    rows[tid] = n_id[r < M ? r : M - 1];
  }
  __syncthreads();
  int tx = tid & 15, ty = tid >> 4;
  int ar = tid >> 2, ak = (tid & 3) * 8;    // A staging: row 0..63, k-offset 0..24
  int wr = tid >> 3, wc = (tid & 7) * 8;    // W staging: k-row 0..31, col-offset
  long arow = (long)rows[ar] * K;
  float acc[4][4] = {};
  for (int k0 = 0; k0 < K; k0 += BK) {
    const float* xp = x + arow + k0 + ak;
    if (k0 + BK <= K) {
#pragma unroll
      for (int j = 0; j < 8; j += 2) {   // row pitch 602 floats => only 8B aligned
        float2 v = *(const float2*)(xp + j);
        As[ar][ak + j] = v.x;
        As[ar][ak + j + 1] = v.y;
      }
    } else {
#pragma unroll
      for (int j = 0; j < 8; j++)
        As[ar][ak + j] = (k0 + ak + j < K) ? xp[j] : 0.f;
    }
    int kg = k0 + wr;
    if (kg < K) {
      const float* wp = W + (size_t)kg * 64 + wc;
      *(float4*)&Bs[wr][wc] = *(const float4*)(wp);
      *(float4*)&Bs[wr][wc + 4] = *(const float4*)(wp + 4);
    } else {
      float4 z = make_float4(0.f, 0.f, 0.f, 0.f);
      *(float4*)&Bs[wr][wc] = z;
      *(float4*)&Bs[wr][wc + 4] = z;
    }
    __syncthreads();
#pragma unroll
    for (int kk = 0; kk < BK; kk++) {
      float a0 = As[ty * 4 + 0][kk];
      float a1 = As[ty * 4 + 1][kk];
      float a2 = As[ty * 4 + 2][kk];
      float a3 = As[ty * 4 + 3][kk];
      float4 b = *(const float4*)&Bs[kk][tx * 4];
      acc[0][0] += a0 * b.x; acc[0][1] += a0 * b.y; acc[0][2] += a0 * b.z; acc[0][3] += a0 * b.w;
      acc[1][0] += a1 * b.x; acc[1][1] += a1 * b.y; acc[1][2] += a1 * b.z; acc[1][3] += a1 * b.w;
      acc[2][0] += a2 * b.x; acc[2][1] += a2 * b.y; acc[2][2] += a2 * b.z; acc[2][3] += a2 * b.w;
      acc[3][0] += a3 * b.x; acc[3][1] += a3 * b.y; acc[3][2] += a3 * b.z; acc[3][3] += a3 * b.w;
    }
    __syncthreads();
  }
#pragma unroll
  for (int i = 0; i < 4; i++) {
    int r = rbase + ty * 4 + i;
    if (r < M) {
      float4 v = make_float4(acc[i][0], acc[i][1], acc[i][2], acc[i][3]);
      *(float4*)&out[(size_t)r * 64 + tx * 4] = v;
    }
  }
}

// ---------------- attention scalars, layer 1 ----------------
__global__ void attn_src1_kernel(const float* __restrict__ hs1, const float* __restrict__ a,
                                 float* __restrict__ s, int N) {
  int t = blockIdx.x * blockDim.x + threadIdx.x;
  if (t >= N * 8) return;
  int i = t >> 3, h = t & 7;
  const float* p = hs1 + (size_t)i * 64 + h * 8;
  const float* q = a + h * 8;
  float acc = 0.f;
#pragma unroll
  for (int j = 0; j < 8; j++) acc += p[j] * q[j];
  s[t] = acc;
}

__global__ void attn_dst1_kernel(const float* __restrict__ hs1, const int* __restrict__ res,
                                 const float* __restrict__ a, float* __restrict__ s, int N) {
  int t = blockIdx.x * blockDim.x + threadIdx.x;
  if (t >= N * 8) return;
  int j = t >> 3, h = t & 7;
  int node = res[j];
  const float* p = hs1 + (size_t)node * 64 + h * 8;
  const float* q = a + h * 8;
  float acc = 0.f;
#pragma unroll
  for (int k = 0; k < 8; k++) acc += p[k] * q[k];
  s[t] = acc;
}

// ---------------- aggregation layer 1: wave per dst node -> h1 (bias+ELU fused) ----------------
__global__ __launch_bounds__(256) void agg1_kernel(
    const int* __restrict__ offs, const int* __restrict__ eidx, const int* __restrict__ esrc,
    const float* __restrict__ s_src, const float* __restrict__ s_dst,
    const float* __restrict__ hs1, const float* __restrict__ bias,
    float* __restrict__ h1, int n_dst) {
  int wid = (blockIdx.x * blockDim.x + threadIdx.x) >> 6;
  if (wid >= n_dst) return;
  int lane = threadIdx.x & 63;
  int h = lane >> 3;
  float sd = s_dst[wid * 8 + h];
  int beg = offs[wid], end = offs[wid + 1];
  float mx = -1e30f;
  for (int i = beg; i < end; i += 4) {
    int m = end - i; if (m > 4) m = 4;
    int e0[4], sr[4]; float ss[4];
#pragma unroll
    for (int j = 0; j < 4; j++) e0[j] = eidx[i + (j < m ? j : 0)];
#pragma unroll
    for (int j = 0; j < 4; j++) sr[j] = esrc[e0[j]];
#pragma unroll
    for (int j = 0; j < 4; j++) ss[j] = s_src[sr[j] * 8 + h];
#pragma unroll
    for (int j = 0; j < 4; j++)
      if (j < m) mx = fmaxf(mx, lrelu02(ss[j] + sd));
  }
  float den = 0.f, acc = 0.f;
  for (int i = beg; i < end; i += 4) {
    int m = end - i; if (m > 4) m = 4;
    int e0[4], sr[4]; float ss[4], row[4];
#pragma unroll
    for (int j = 0; j < 4; j++) e0[j] = eidx[i + (j < m ? j : 0)];
#pragma unroll
    for (int j = 0; j < 4; j++) sr[j] = esrc[e0[j]];
#pragma unroll
    for (int j = 0; j < 4; j++) ss[j] = s_src[sr[j] * 8 + h];
#pragma unroll
    for (int j = 0; j < 4; j++) row[j] = hs1[(size_t)sr[j] * 64 + lane];
#pragma unroll
    for (int j = 0; j < 4; j++)
      if (j < m) {
        float p = __expf(lrelu02(ss[j] + sd) - mx);
        den += p;
        acc += p * row[j];
      }
  }
  float val = (end > beg) ? acc / den : 0.f;
  val += bias[lane];
  val = val > 0.f ? val : __expf(val) - 1.f;  // ELU
  h1[(size_t)wid * 64 + lane] = val;
}

// ---------------- GEMM2 + s_src2: hs2 = h1 @ W2 (30000x64 @ 64x41) ----------------
__global__ __launch_bounds__(256) void gemm2_kernel(const float* __restrict__ h1,
                                                    const float* __restrict__ W2,
                                                    const float* __restrict__ a_src,
                                                    float* __restrict__ hs2,
                                                    float* __restrict__ ssrc, int M) {
  constexpr int C = 41;
  __shared__ float Ws[64 * C];
  for (int i = threadIdx.x; i < 64 * C; i += 256) Ws[i] = W2[i];
  __syncthreads();
  int lane = threadIdx.x & 63;
  int r = blockIdx.x * 4 + (threadIdx.x >> 6);
  if (r >= M) return;
  const float* row = h1 + (size_t)r * 64;
  float acc = 0.f;
  if (lane < C) {
#pragma unroll 8
    for (int k = 0; k < 64; k++) acc += row[k] * Ws[k * C + lane];
  }
  float t = (lane < C) ? acc * a_src[lane] : 0.f;
  t = wave_sum64(t);
  if (lane == 0) ssrc[r] = t;
  if (lane < C) hs2[(size_t)r * C + lane] = acc;
}

__global__ void attn_dst2_kernel(const float* __restrict__ hs2, const int* __restrict__ res,
                                 const float* __restrict__ a, float* __restrict__ s, int N) {
  constexpr int C = 41;
  int wid = (blockIdx.x * blockDim.x + threadIdx.x) >> 6;
  int lane = threadIdx.x & 63;
  if (wid >= N) return;
  int node = res[wid];
  float v = (lane < C) ? hs2[(size_t)node * C + lane] * a[lane] : 0.f;
  v = wave_sum64(v);
  if (lane == 0) s[wid] = v;
}

// ---------------- aggregation layer 2 + bias + log_softmax ----------------
__global__ __launch_bounds__(256) void agg2_kernel(
    const int* __restrict__ offs, const int* __restrict__ eidx, const int* __restrict__ esrc,
    const float* __restrict__ s_src, const float* __restrict__ s_dst,
    const float* __restrict__ hs2, const float* __restrict__ bias,
    float* __restrict__ out, int n_dst) {
  constexpr int C = 41;
  int wid = (blockIdx.x * blockDim.x + threadIdx.x) >> 6;
  if (wid >= n_dst) return;
  int lane = threadIdx.x & 63;
  bool act = lane < C;
  float sd = s_dst[wid];
  int beg = offs[wid], end = offs[wid + 1];
  float mx = -1e30f;
  for (int i = beg; i < end; i += 4) {
    int m = end - i; if (m > 4) m = 4;
    int e0[4], sr[4]; float ss[4];
#pragma unroll
    for (int j = 0; j < 4; j++) e0[j] = eidx[i + (j < m ? j : 0)];
#pragma unroll
    for (int j = 0; j < 4; j++) sr[j] = esrc[e0[j]];
#pragma unroll
    for (int j = 0; j < 4; j++) ss[j] = s_src[sr[j]];
#pragma unroll
    for (int j = 0; j < 4; j++)
      if (j < m) mx = fmaxf(mx, lrelu02(ss[j] + sd));
  }
  float den = 0.f, acc = 0.f;
  for (int i = beg; i < end; i += 4) {
    int m = end - i; if (m > 4) m = 4;
    int e0[4], sr[4]; float ss[4], row[4];
#pragma unroll
    for (int j = 0; j < 4; j++) e0[j] = eidx[i + (j < m ? j : 0)];
#pragma unroll
    for (int j = 0; j < 4; j++) sr[j] = esrc[e0[j]];
#pragma unroll
    for (int j = 0; j < 4; j++) ss[j] = s_src[sr[j]];
#pragma unroll
    for (int j = 0; j < 4; j++) row[j] = act ? hs2[(size_t)sr[j] * C + lane] : 0.f;
#pragma unroll
    for (int j = 0; j < 4; j++)
      if (j < m) {
        float p = __expf(lrelu02(ss[j] + sd) - mx);
        den += p;
        acc += p * row[j];
      }
  }
  float val = (end > beg) ? acc / den : 0.f;
  if (act) val += bias[lane];
  float lv = act ? val : -1e30f;
  float m2 = wave_max64(lv);
  float ex = act ? __expf(val - m2) : 0.f;
  float ssum = wave_sum64(ex);
  if (act) out[(size_t)wid * C + lane] = val - m2 - __logf(ssum);
}

// ---------------- launch ----------------
extern "C" void kernel_launch(void* const* d_in, const int* in_sizes, int n_in,
                              void* d_out, int out_size, void* d_ws, size_t ws_size,
                              hipStream_t stream) {
  const float* x    = (const float*)d_in[0];
  const int* n_id1  = (const int*)d_in[1];
  const int* res1   = (const int*)d_in[2];
  const int* esrc1  = (const int*)d_in[3];
  const int* edst1  = (const int*)d_in[4];
  const int* res2   = (const int*)d_in[5];
  const int* esrc2  = (const int*)d_in[6];
  const int* edst2  = (const int*)d_in[7];
  const float* W1   = (const float*)d_in[8];
  const float* as1  = (const float*)d_in[9];
  const float* ad1  = (const float*)d_in[10];
  const float* b1   = (const float*)d_in[11];
  const float* W2   = (const float*)d_in[12];
  const float* as2  = (const float*)d_in[13];
  const float* ad2  = (const float*)d_in[14];
  const float* b2   = (const float*)d_in[15];
  float* out = (float*)d_out;

  const int N1  = in_sizes[1];  // 120000
  const int N1D = in_sizes[2];  // 30000
  const int E1  = in_sizes[3];  // 960000
  const int N2D = in_sizes[5];  // 6000
  const int E2  = in_sizes[6];  // 192000

  char* w = (char*)d_ws;
  size_t off = 0;
  auto alloc = [&](size_t bytes) -> void* {
    void* p = (void*)(w + off);
    off += (bytes + 255) & ~(size_t)255;
    return p;
  };
  float* hs1   = (float*)alloc((size_t)N1 * 64 * 4);
  float* ssrc1 = (float*)alloc((size_t)N1 * 8 * 4);
  float* sdst1 = (float*)alloc((size_t)N1D * 8 * 4);
  float* h1    = (float*)alloc((size_t)N1D * 64 * 4);
  float* hs2   = (float*)alloc((size_t)N1D * 41 * 4);
  float* ssrc2 = (float*)alloc((size_t)N1D * 4);
  float* sdst2 = (float*)alloc((size_t)N2D * 4);
  int* counters = (int*)alloc((size_t)(2 * N1D + 2 * N2D) * 4);
  int* counts1 = counters;
  int* cursor1 = counters + N1D;
  int* counts2 = counters + 2 * N1D;
  int* cursor2 = counters + 2 * N1D + N2D;
  int* offs1 = (int*)alloc((size_t)(N1D + 1) * 4);
  int* offs2 = (int*)alloc((size_t)(N2D + 1) * 4);
  int* eidx1 = (int*)alloc((size_t)E1 * 4);
  int* eidx2 = (int*)alloc((size_t)E2 * 4);
  (void)ws_size; (void)n_in; (void)out_size; (void)sdst2;

  hipMemsetAsync(counters, 0, (size_t)(2 * N1D + 2 * N2D) * 4, stream);

  // CSR build for both layers
  hist_kernel<<<(E1 + 255) / 256, 256, 0, stream>>>(edst1, counts1, E1);
  hist_kernel<<<(E2 + 255) / 256, 256, 0, stream>>>(edst2, counts2, E2);
  scan_kernel<<<1, 1024, 0, stream>>>(counts1, offs1, N1D);
  scan_kernel<<<1, 1024, 0, stream>>>(counts2, offs2, N2D);
  scatter_kernel<<<(E1 + 255) / 256, 256, 0, stream>>>(edst1, offs1, cursor1, eidx1, E1);
  scatter_kernel<<<(E2 + 255) / 256, 256, 0, stream>>>(edst2, offs2, cursor2, eidx2, E2);

  // layer 1
  gemm1_kernel<<<(N1 + 63) / 64, 256, 0, stream>>>(x, n_id1, W1, hs1, N1);
  attn_src1_kernel<<<(N1 * 8 + 255) / 256, 256, 0, stream>>>(hs1, as1, ssrc1, N1);
  attn_dst1_kernel<<<(N1D * 8 + 255) / 256, 256, 0, stream>>>(hs1, res1, ad1, sdst1, N1D);
  agg1_kernel<<<(N1D + 3) / 4, 256, 0, stream>>>(offs1, eidx1, esrc1, ssrc1, sdst1, hs1, b1, h1, N1D);

  // layer 2
  gemm2_kernel<<<(N1D + 3) / 4, 256, 0, stream>>>(h1, W2, as2, hs2, ssrc2, N1D);
  attn_dst2_kernel<<<(N2D + 3) / 4, 256, 0, stream>>>(hs2, res2, ad2, sdst2, N2D);
  agg2_kernel<<<(N2D + 3) / 4, 256, 0, stream>>>(offs2, eidx2, esrc2, ssrc2, sdst2, hs2, b2, out, N2D);
}

// Round 3
// 871.980 us; speedup vs baseline: 1.2279x; 1.2279x over previous
//
#include <hip/hip_runtime.h>
#include <hip/hip_bf16.h>
#include <math.h>

typedef __attribute__((ext_vector_type(8))) short short8;
typedef __attribute__((ext_vector_type(4))) float float4v;

// ---------------- helpers ----------------
__device__ __forceinline__ float wave_max64(float v) {
#pragma unroll
  for (int o = 32; o > 0; o >>= 1) v = fmaxf(v, __shfl_xor(v, o));
  return v;
}
__device__ __forceinline__ float wave_sum64(float v) {
#pragma unroll
  for (int o = 32; o > 0; o >>= 1) v += __shfl_xor(v, o);
  return v;
}
__device__ __forceinline__ float lrelu02(float v) { return v > 0.f ? v : 0.2f * v; }
__device__ __forceinline__ short bf16_rne(float f) {
  unsigned u = __builtin_bit_cast(unsigned, f);
  unsigned r = (u + 0x7FFFu + ((u >> 16) & 1u)) >> 16;
  return (short)r;
}

// ---------------- CSR build (both layers fused; layer2 ids offset by N1D) ----------------
__global__ void hist_kernel(const int* __restrict__ dst1, const int* __restrict__ dst2,
                            int* __restrict__ counts, int E1, int E2, int N1D) {
  int e = blockIdx.x * blockDim.x + threadIdx.x;
  if (e < E1) atomicAdd(&counts[dst1[e]], 1);
  else if (e < E1 + E2) atomicAdd(&counts[N1D + dst2[e - E1]], 1);
}

// two-level scan over n = N1D + N2D elements
__global__ __launch_bounds__(256) void scan1_kernel(const int* __restrict__ counts,
                                                    int* __restrict__ offs,
                                                    int* __restrict__ bsum, int n) {
  __shared__ int ws[4], wpre[4];
  int tid = threadIdx.x, lane = tid & 63, w = tid >> 6;
  int i = blockIdx.x * 256 + tid;
  int v = (i < n) ? counts[i] : 0;
  int x = v;
#pragma unroll
  for (int o = 1; o < 64; o <<= 1) {
    int y = __shfl_up(x, o);
    if (lane >= o) x += y;
  }
  if (lane == 63) ws[w] = x;
  __syncthreads();
  if (tid == 0) {
    int run = 0;
#pragma unroll
    for (int k = 0; k < 4; k++) { wpre[k] = run; run += ws[k]; }
    bsum[blockIdx.x] = run;
  }
  __syncthreads();
  if (i < n) offs[i] = x - v + wpre[w];  // exclusive within block
}

__global__ __launch_bounds__(256) void scan2_kernel(int* __restrict__ bsum, int nb) {
  __shared__ int ws[4], wpre[4];
  int tid = threadIdx.x, lane = tid & 63, w = tid >> 6;
  int v = (tid < nb) ? bsum[tid] : 0;
  int x = v;
#pragma unroll
  for (int o = 1; o < 64; o <<= 1) {
    int y = __shfl_up(x, o);
    if (lane >= o) x += y;
  }
  if (lane == 63) ws[w] = x;
  __syncthreads();
  if (tid == 0) {
    int run = 0;
#pragma unroll
    for (int k = 0; k < 4; k++) { wpre[k] = run; run += ws[k]; }
  }
  __syncthreads();
  if (tid < nb) bsum[tid] = x - v + wpre[w];  // exclusive block prefixes
}

__global__ __launch_bounds__(256) void scan3_kernel(int* __restrict__ offs,
                                                    const int* __restrict__ bsum,
                                                    int n, int etot) {
  int i = blockIdx.x * 256 + threadIdx.x;
  if (i < n) offs[i] += bsum[blockIdx.x];
  if (i == 0) offs[n] = etot;  // sentinel
}

__global__ void scatter_kernel(const int* __restrict__ dst1, const int* __restrict__ dst2,
                               const int* __restrict__ offs, int* __restrict__ cursor,
                               int* __restrict__ eidx, int E1, int E2, int N1D) {
  int e = blockIdx.x * blockDim.x + threadIdx.x;
  if (e < E1) {
    int d = dst1[e];
    int pos = offs[d] + atomicAdd(&cursor[d], 1);
    eidx[pos] = e;
  } else if (e < E1 + E2) {
    int e2 = e - E1;
    int d = N1D + dst2[e2];
    int pos = offs[d] + atomicAdd(&cursor[d], 1);
    eidx[pos] = e2;  // layer-2 local edge id
  }
}

// ---------------- W1 pre-pack into MFMA B-fragment order (bf16) ----------------
// Wp[((s*4 + t)*64 + lane)*8 + j] = bf16(W[k][n]), k = s*32 + (lane>>4)*8 + j,
// n = t*16 + (lane&15); zero-filled for k >= 602.
__global__ void prepack_W1_kernel(const float* __restrict__ W, short* __restrict__ Wp) {
  int idx = blockIdx.x * 256 + threadIdx.x;  // over 19*4*64 = 4864
  if (idx >= 19 * 4 * 64) return;
  int lane = idx & 63;
  int t = (idx >> 6) & 3;
  int s = idx >> 8;
  int quad = lane >> 4, n = t * 16 + (lane & 15);
  short8 v;
#pragma unroll
  for (int j = 0; j < 8; j++) {
    int k = s * 32 + quad * 8 + j;
    v[j] = (k < 602) ? bf16_rne(W[k * 64 + n]) : (short)0;
  }
  *((short8*)Wp + idx) = v;
}

// ---------------- GEMM1 (MFMA bf16): hs1 = x[n_id1] @ W1, M x 602 @ 602 x 64 -------------
// Block = 256 threads = 4 waves; wave computes 16 rows x 64 cols. No LDS.
__global__ __launch_bounds__(256) void gemm1_mfma_kernel(const float* __restrict__ x,
                                                         const int* __restrict__ n_id,
                                                         const short* __restrict__ Wp,
                                                         float* __restrict__ out, int M) {
  constexpr int K = 602, NSTEP = 19;
  int tid = threadIdx.x;
  int wid = tid >> 6, lane = tid & 63;
  int quad = lane >> 4, mrow = lane & 15;
  int r = blockIdx.x * 64 + wid * 16 + mrow;
  int grow = n_id[r < M ? r : M - 1];
  const float* xrow = x + (size_t)grow * K;
  float4v acc[4] = {{0.f, 0.f, 0.f, 0.f}, {0.f, 0.f, 0.f, 0.f},
                    {0.f, 0.f, 0.f, 0.f}, {0.f, 0.f, 0.f, 0.f}};
  for (int s = 0; s < NSTEP; s++) {
    int k0 = s * 32 + quad * 8;
    float af[8];
    if (k0 + 8 <= K) {  // 8B-aligned (row pitch 602 even, k0 even)
#pragma unroll
      for (int j = 0; j < 8; j += 2) {
        float2 v = *(const float2*)(xrow + k0 + j);
        af[j] = v.x;
        af[j + 1] = v.y;
      }
    } else {
#pragma unroll
      for (int j = 0; j < 8; j++) af[j] = (k0 + j < K) ? xrow[k0 + j] : 0.f;
    }
    short8 a;
#pragma unroll
    for (int j = 0; j < 8; j++) a[j] = bf16_rne(af[j]);
    const short8* wp = (const short8*)Wp + (size_t)s * 256 + lane;
#pragma unroll
    for (int t = 0; t < 4; t++) {
      short8 b = wp[t * 64];
      acc[t] = __builtin_amdgcn_mfma_f32_16x16x32_bf16(a, b, acc[t], 0, 0, 0);
    }
  }
  int rb = blockIdx.x * 64 + wid * 16;
#pragma unroll
  for (int t = 0; t < 4; t++) {
#pragma unroll
    for (int j = 0; j < 4; j++) {
      int rr = rb + quad * 4 + j;  // C/D: col = lane&15, row = quad*4 + reg
      if (rr < M) out[(size_t)rr * 64 + t * 16 + mrow] = acc[t][j];
    }
  }
}

// ---------------- attention scalars, layer 1 ----------------
__global__ void attn_src1_kernel(const float* __restrict__ hs1, const float* __restrict__ a,
                                 float* __restrict__ s, int N) {
  int t = blockIdx.x * blockDim.x + threadIdx.x;
  if (t >= N * 8) return;
  int i = t >> 3, h = t & 7;
  const float* p = hs1 + (size_t)i * 64 + h * 8;
  const float* q = a + h * 8;
  float acc = 0.f;
#pragma unroll
  for (int j = 0; j < 8; j++) acc += p[j] * q[j];
  s[t] = acc;
}

__global__ void attn_dst1_kernel(const float* __restrict__ hs1, const int* __restrict__ res,
                                 const float* __restrict__ a, float* __restrict__ s, int N) {
  int t = blockIdx.x * blockDim.x + threadIdx.x;
  if (t >= N * 8) return;
  int j = t >> 3, h = t & 7;
  int node = res[j];
  const float* p = hs1 + (size_t)node * 64 + h * 8;
  const float* q = a + h * 8;
  float acc = 0.f;
#pragma unroll
  for (int k = 0; k < 8; k++) acc += p[k] * q[k];
  s[t] = acc;
}

// ---------------- aggregation layer 1 (online softmax, single pass) ----------------
__global__ __launch_bounds__(256) void agg1_kernel(
    const int* __restrict__ offs, const int* __restrict__ eidx, const int* __restrict__ esrc,
    const float* __restrict__ s_src, const float* __restrict__ s_dst,
    const float* __restrict__ hs1, const float* __restrict__ bias,
    float* __restrict__ h1, int n_dst) {
  int wid = (blockIdx.x * blockDim.x + threadIdx.x) >> 6;
  if (wid >= n_dst) return;
  int lane = threadIdx.x & 63;
  int h = lane >> 3;
  float sd = s_dst[wid * 8 + h];
  int beg = offs[wid], end = offs[wid + 1];
  float mx = -1e30f, den = 0.f, acc = 0.f;
  for (int i = beg; i < end; i += 4) {
    int m = end - i; if (m > 4) m = 4;
    int e0[4], sr[4]; float ss[4], row[4];
#pragma unroll
    for (int j = 0; j < 4; j++) e0[j] = eidx[i + (j < m ? j : 0)];
#pragma unroll
    for (int j = 0; j < 4; j++) sr[j] = esrc[e0[j]];
#pragma unroll
    for (int j = 0; j < 4; j++) ss[j] = s_src[sr[j] * 8 + h];
#pragma unroll
    for (int j = 0; j < 4; j++) row[j] = hs1[(size_t)sr[j] * 64 + lane];
    float p[4];
#pragma unroll
    for (int j = 0; j < 4; j++) p[j] = (j < m) ? lrelu02(ss[j] + sd) : -1e30f;
    float bm = mx;
#pragma unroll
    for (int j = 0; j < 4; j++) bm = fmaxf(bm, p[j]);
    float scale = __expf(mx - bm);
    den *= scale;
    acc *= scale;
#pragma unroll
    for (int j = 0; j < 4; j++) {
      float w = __expf(p[j] - bm);
      den += w;
      acc += w * row[j];
    }
    mx = bm;
  }
  float val = (end > beg) ? acc / den : 0.f;
  val += bias[lane];
  val = val > 0.f ? val : __expf(val) - 1.f;  // ELU
  h1[(size_t)wid * 64 + lane] = val;
}

// ---------------- GEMM2 + s_src2: hs2 = h1 @ W2 (30000x64 @ 64x41) ----------------
__global__ __launch_bounds__(256) void gemm2_kernel(const float* __restrict__ h1,
                                                    const float* __restrict__ W2,
                                                    const float* __restrict__ a_src,
                                                    float* __restrict__ hs2,
                                                    float* __restrict__ ssrc, int M) {
  constexpr int C = 41;
  __shared__ float Ws[64 * C];
  for (int i = threadIdx.x; i < 64 * C; i += 256) Ws[i] = W2[i];
  __syncthreads();
  int lane = threadIdx.x & 63;
  int r = blockIdx.x * 4 + (threadIdx.x >> 6);
  if (r >= M) return;
  const float* row = h1 + (size_t)r * 64;
  float acc = 0.f;
  if (lane < C) {
#pragma unroll 8
    for (int k = 0; k < 64; k++) acc += row[k] * Ws[k * C + lane];
  }
  float t = (lane < C) ? acc * a_src[lane] : 0.f;
  t = wave_sum64(t);
  if (lane == 0) ssrc[r] = t;
  if (lane < C) hs2[(size_t)r * C + lane] = acc;
}

__global__ void attn_dst2_kernel(const float* __restrict__ hs2, const int* __restrict__ res,
                                 const float* __restrict__ a, float* __restrict__ s, int N) {
  constexpr int C = 41;
  int wid = (blockIdx.x * blockDim.x + threadIdx.x) >> 6;
  int lane = threadIdx.x & 63;
  if (wid >= N) return;
  int node = res[wid];
  float v = (lane < C) ? hs2[(size_t)node * C + lane] * a[lane] : 0.f;
  v = wave_sum64(v);
  if (lane == 0) s[wid] = v;
}

// ---------------- aggregation layer 2 (online softmax) + bias + log_softmax ----------------
__global__ __launch_bounds__(256) void agg2_kernel(
    const int* __restrict__ offs, const int* __restrict__ eidx, const int* __restrict__ esrc,
    const float* __restrict__ s_src, const float* __restrict__ s_dst,
    const float* __restrict__ hs2, const float* __restrict__ bias,
    float* __restrict__ out, int n_dst) {
  constexpr int C = 41;
  int wid = (blockIdx.x * blockDim.x + threadIdx.x) >> 6;
  if (wid >= n_dst) return;
  int lane = threadIdx.x & 63;
  bool act = lane < C;
  float sd = s_dst[wid];
  int beg = offs[wid], end = offs[wid + 1];
  float mx = -1e30f, den = 0.f, acc = 0.f;
  for (int i = beg; i < end; i += 4) {
    int m = end - i; if (m > 4) m = 4;
    int e0[4], sr[4]; float ss[4], row[4];
#pragma unroll
    for (int j = 0; j < 4; j++) e0[j] = eidx[i + (j < m ? j : 0)];
#pragma unroll
    for (int j = 0; j < 4; j++) sr[j] = esrc[e0[j]];
#pragma unroll
    for (int j = 0; j < 4; j++) ss[j] = s_src[sr[j]];
#pragma unroll
    for (int j = 0; j < 4; j++) row[j] = act ? hs2[(size_t)sr[j] * C + lane] : 0.f;
    float p[4];
#pragma unroll
    for (int j = 0; j < 4; j++) p[j] = (j < m) ? lrelu02(ss[j] + sd) : -1e30f;
    float bm = mx;
#pragma unroll
    for (int j = 0; j < 4; j++) bm = fmaxf(bm, p[j]);
    float scale = __expf(mx - bm);
    den *= scale;
    acc *= scale;
#pragma unroll
    for (int j = 0; j < 4; j++) {
      float w = __expf(p[j] - bm);
      den += w;
      acc += w * row[j];
    }
    mx = bm;
  }
  float val = (end > beg) ? acc / den : 0.f;
  if (act) val += bias[lane];
  float lv = act ? val : -1e30f;
  float m2 = wave_max64(lv);
  float ex = act ? __expf(val - m2) : 0.f;
  float ssum = wave_sum64(ex);
  if (act) out[(size_t)wid * C + lane] = val - m2 - __logf(ssum);
}

// ---------------- launch ----------------
extern "C" void kernel_launch(void* const* d_in, const int* in_sizes, int n_in,
                              void* d_out, int out_size, void* d_ws, size_t ws_size,
                              hipStream_t stream) {
  const float* x    = (const float*)d_in[0];
  const int* n_id1  = (const int*)d_in[1];
  const int* res1   = (const int*)d_in[2];
  const int* esrc1  = (const int*)d_in[3];
  const int* edst1  = (const int*)d_in[4];
  const int* res2   = (const int*)d_in[5];
  const int* esrc2  = (const int*)d_in[6];
  const int* edst2  = (const int*)d_in[7];
  const float* W1   = (const float*)d_in[8];
  const float* as1  = (const float*)d_in[9];
  const float* ad1  = (const float*)d_in[10];
  const float* b1   = (const float*)d_in[11];
  const float* W2   = (const float*)d_in[12];
  const float* as2  = (const float*)d_in[13];
  const float* ad2  = (const float*)d_in[14];
  const float* b2   = (const float*)d_in[15];
  float* out = (float*)d_out;

  const int N1  = in_sizes[1];  // 120000
  const int N1D = in_sizes[2];  // 30000
  const int E1  = in_sizes[3];  // 960000
  const int N2D = in_sizes[5];  // 6000
  const int E2  = in_sizes[6];  // 192000
  const int NTOT = N1D + N2D;
  const int ETOT = E1 + E2;

  char* w = (char*)d_ws;
  size_t off = 0;
  auto alloc = [&](size_t bytes) -> void* {
    void* p = (void*)(w + off);
    off += (bytes + 255) & ~(size_t)255;
    return p;
  };
  float* hs1   = (float*)alloc((size_t)N1 * 64 * 4);
  float* ssrc1 = (float*)alloc((size_t)N1 * 8 * 4);
  float* sdst1 = (float*)alloc((size_t)N1D * 8 * 4);
  float* h1    = (float*)alloc((size_t)N1D * 64 * 4);
  float* hs2   = (float*)alloc((size_t)N1D * 41 * 4);
  float* ssrc2 = (float*)alloc((size_t)N1D * 4);
  float* sdst2 = (float*)alloc((size_t)N2D * 4);
  // counts+cursor in ONE contiguous alloc: the single memset below must cover
  // both exactly (round-2 bug: separate 256-aligned allocs left a 128 B
  // poisoned gap inside cursor -> wild eidx writes -> GPU abort).
  int* counts  = (int*)alloc((size_t)2 * NTOT * 4);
  int* cursor  = counts + NTOT;
  int* offs    = (int*)alloc((size_t)(NTOT + 1) * 4);
  int* bsum    = (int*)alloc((size_t)256 * 4);
  int* eidx    = (int*)alloc((size_t)ETOT * 4);
  short* Wp    = (short*)alloc((size_t)19 * 4 * 64 * 8 * 2);
  (void)ws_size; (void)n_in; (void)out_size;

  hipMemsetAsync(counts, 0, (size_t)2 * NTOT * 4, stream);  // counts + cursor exactly

  // W1 pre-pack (bf16 fragment order)
  prepack_W1_kernel<<<19, 256, 0, stream>>>(W1, Wp);

  // CSR build, both layers fused
  const int nb = (NTOT + 255) / 256;  // 141
  hist_kernel<<<(ETOT + 255) / 256, 256, 0, stream>>>(edst1, edst2, counts, E1, E2, N1D);
  scan1_kernel<<<nb, 256, 0, stream>>>(counts, offs, bsum, NTOT);
  scan2_kernel<<<1, 256, 0, stream>>>(bsum, nb);
  scan3_kernel<<<nb, 256, 0, stream>>>(offs, bsum, NTOT, ETOT);
  scatter_kernel<<<(ETOT + 255) / 256, 256, 0, stream>>>(edst1, edst2, offs, cursor, eidx, E1, E2, N1D);

  // layer 1
  gemm1_mfma_kernel<<<(N1 + 63) / 64, 256, 0, stream>>>(x, n_id1, Wp, hs1, N1);
  attn_src1_kernel<<<(N1 * 8 + 255) / 256, 256, 0, stream>>>(hs1, as1, ssrc1, N1);
  attn_dst1_kernel<<<(N1D * 8 + 255) / 256, 256, 0, stream>>>(hs1, res1, ad1, sdst1, N1D);
  agg1_kernel<<<(N1D + 3) / 4, 256, 0, stream>>>(offs, eidx, esrc1, ssrc1, sdst1, hs1, b1, h1, N1D);

  // layer 2 (CSR segment 2 lives at offs + N1D, eidx ids are layer-local)
  gemm2_kernel<<<(N1D + 3) / 4, 256, 0, stream>>>(h1, W2, as2, hs2, ssrc2, N1D);
  attn_dst2_kernel<<<(N2D + 3) / 4, 256, 0, stream>>>(hs2, res2, ad2, sdst2, N2D);
  agg2_kernel<<<(N2D + 3) / 4, 256, 0, stream>>>(offs + N1D, eidx, esrc2, ssrc2, sdst2, hs2, b2, out, N2D);
}

// Round 4
// 840.435 us; speedup vs baseline: 1.2740x; 1.0375x over previous
//
#include <hip/hip_runtime.h>
#include <hip/hip_bf16.h>
#include <math.h>

typedef __attribute__((ext_vector_type(8))) short short8;
typedef __attribute__((ext_vector_type(4))) float float4v;

// ---------------- helpers ----------------
__device__ __forceinline__ float wave_max64(float v) {
#pragma unroll
  for (int o = 32; o > 0; o >>= 1) v = fmaxf(v, __shfl_xor(v, o));
  return v;
}
__device__ __forceinline__ float wave_sum64(float v) {
#pragma unroll
  for (int o = 32; o > 0; o >>= 1) v += __shfl_xor(v, o);
  return v;
}
__device__ __forceinline__ float lrelu02(float v) { return v > 0.f ? v : 0.2f * v; }
__device__ __forceinline__ short bf16_rne(float f) {
  unsigned u = __builtin_bit_cast(unsigned, f);
  unsigned r = (u + 0x7FFFu + ((u >> 16) & 1u)) >> 16;
  return (short)r;
}

// ---------------- hist (both layers) + W1 prepack, merged ----------------
// blocks [0, nbE): histogram; blocks [nbE, nbE+19): prepack W1 into MFMA
// B-fragment order: Wp[((s*4+t)*64+lane)*8+j] = bf16(W[k][n]),
// k = s*32 + (lane>>4)*8 + j, n = t*16 + (lane&15); zero for k >= 602.
__global__ void hist_prepack_kernel(const int* __restrict__ dst1, const int* __restrict__ dst2,
                                    int* __restrict__ counts, const float* __restrict__ W,
                                    short* __restrict__ Wp, int E1, int E2, int N1D, int nbE) {
  int b = blockIdx.x;
  if (b < nbE) {
    int e = b * 256 + threadIdx.x;
    if (e < E1) atomicAdd(&counts[dst1[e]], 1);
    else if (e < E1 + E2) atomicAdd(&counts[N1D + dst2[e - E1]], 1);
  } else {
    int idx = (b - nbE) * 256 + threadIdx.x;  // over 19*4*64 = 4864
    if (idx >= 19 * 4 * 64) return;
    int lane = idx & 63;
    int t = (idx >> 6) & 3;
    int s = idx >> 8;
    int quad = lane >> 4, n = t * 16 + (lane & 15);
    short8 v;
#pragma unroll
    for (int j = 0; j < 8; j++) {
      int k = s * 32 + quad * 8 + j;
      v[j] = (k < 602) ? bf16_rne(W[k * 64 + n]) : (short)0;
    }
    *((short8*)Wp + idx) = v;
  }
}

// two-level scan over n = N1D + N2D elements
__global__ __launch_bounds__(256) void scan1_kernel(const int* __restrict__ counts,
                                                    int* __restrict__ offs,
                                                    int* __restrict__ bsum, int n) {
  __shared__ int ws[4], wpre[4];
  int tid = threadIdx.x, lane = tid & 63, w = tid >> 6;
  int i = blockIdx.x * 256 + tid;
  int v = (i < n) ? counts[i] : 0;
  int x = v;
#pragma unroll
  for (int o = 1; o < 64; o <<= 1) {
    int y = __shfl_up(x, o);
    if (lane >= o) x += y;
  }
  if (lane == 63) ws[w] = x;
  __syncthreads();
  if (tid == 0) {
    int run = 0;
#pragma unroll
    for (int k = 0; k < 4; k++) { wpre[k] = run; run += ws[k]; }
    bsum[blockIdx.x] = run;
  }
  __syncthreads();
  if (i < n) offs[i] = x - v + wpre[w];  // exclusive within block
}

__global__ __launch_bounds__(256) void scan2_kernel(int* __restrict__ bsum, int nb) {
  __shared__ int ws[4], wpre[4];
  int tid = threadIdx.x, lane = tid & 63, w = tid >> 6;
  int v = (tid < nb) ? bsum[tid] : 0;
  int x = v;
#pragma unroll
  for (int o = 1; o < 64; o <<= 1) {
    int y = __shfl_up(x, o);
    if (lane >= o) x += y;
  }
  if (lane == 63) ws[w] = x;
  __syncthreads();
  if (tid == 0) {
    int run = 0;
#pragma unroll
    for (int k = 0; k < 4; k++) { wpre[k] = run; run += ws[k]; }
  }
  __syncthreads();
  if (tid < nb) bsum[tid] = x - v + wpre[w];  // exclusive block prefixes
}

__global__ __launch_bounds__(256) void scan3_kernel(int* __restrict__ offs,
                                                    const int* __restrict__ bsum,
                                                    int n, int etot) {
  int i = blockIdx.x * 256 + threadIdx.x;
  if (i < n) offs[i] += bsum[blockIdx.x];
  if (i == 0) offs[n] = etot;  // sentinel
}

// scatter stores the SOURCE NODE id (payload) directly into the CSR slot:
// aggregation is order-independent, so slot order doesn't matter, and this
// removes one level of the dependent gather chain in the agg kernels.
__global__ void scatter_kernel(const int* __restrict__ dst1, const int* __restrict__ src1,
                               const int* __restrict__ dst2, const int* __restrict__ src2,
                               const int* __restrict__ offs, int* __restrict__ cursor,
                               int* __restrict__ epay, int E1, int E2, int N1D) {
  int e = blockIdx.x * blockDim.x + threadIdx.x;
  if (e < E1) {
    int d = dst1[e];
    int pos = offs[d] + atomicAdd(&cursor[d], 1);
    epay[pos] = src1[e];
  } else if (e < E1 + E2) {
    int e2 = e - E1;
    int d = N1D + dst2[e2];
    int pos = offs[d] + atomicAdd(&cursor[d], 1);
    epay[pos] = src2[e2];
  }
}

// ---------------- GEMM1 (MFMA bf16): hs1 = x[n_id1] @ W1, M x 602 @ 602 x 64 -------------
// Block = 256 threads = 4 waves; wave computes 16 rows x 64 cols. No LDS.
__global__ __launch_bounds__(256) void gemm1_mfma_kernel(const float* __restrict__ x,
                                                         const int* __restrict__ n_id,
                                                         const short* __restrict__ Wp,
                                                         float* __restrict__ out, int M) {
  constexpr int K = 602, NSTEP = 19;
  int tid = threadIdx.x;
  int wid = tid >> 6, lane = tid & 63;
  int quad = lane >> 4, mrow = lane & 15;
  int r = blockIdx.x * 64 + wid * 16 + mrow;
  int grow = n_id[r < M ? r : M - 1];
  const float* xrow = x + (size_t)grow * K;
  float4v acc[4] = {{0.f, 0.f, 0.f, 0.f}, {0.f, 0.f, 0.f, 0.f},
                    {0.f, 0.f, 0.f, 0.f}, {0.f, 0.f, 0.f, 0.f}};
  for (int s = 0; s < NSTEP; s++) {
    int k0 = s * 32 + quad * 8;
    float af[8];
    if (k0 + 8 <= K) {  // 8B-aligned (row pitch 602 even, k0 even)
#pragma unroll
      for (int j = 0; j < 8; j += 2) {
        float2 v = *(const float2*)(xrow + k0 + j);
        af[j] = v.x;
        af[j + 1] = v.y;
      }
    } else {
#pragma unroll
      for (int j = 0; j < 8; j++) af[j] = (k0 + j < K) ? xrow[k0 + j] : 0.f;
    }
    short8 a;
#pragma unroll
    for (int j = 0; j < 8; j++) a[j] = bf16_rne(af[j]);
    const short8* wp = (const short8*)Wp + (size_t)s * 256 + lane;
#pragma unroll
    for (int t = 0; t < 4; t++) {
      short8 b = wp[t * 64];
      acc[t] = __builtin_amdgcn_mfma_f32_16x16x32_bf16(a, b, acc[t], 0, 0, 0);
    }
  }
  int rb = blockIdx.x * 64 + wid * 16;
#pragma unroll
  for (int t = 0; t < 4; t++) {
#pragma unroll
    for (int j = 0; j < 4; j++) {
      int rr = rb + quad * 4 + j;  // C/D: col = lane&15, row = quad*4 + reg
      if (rr < M) out[(size_t)rr * 64 + t * 16 + mrow] = acc[t][j];
    }
  }
}

// ---------------- attention src scalars, layer 1 ----------------
__global__ void attn_src1_kernel(const float* __restrict__ hs1, const float* __restrict__ a,
                                 float* __restrict__ s, int N) {
  int t = blockIdx.x * blockDim.x + threadIdx.x;
  if (t >= N * 8) return;
  int i = t >> 3, h = t & 7;
  const float* p = hs1 + (size_t)i * 64 + h * 8;
  const float* q = a + h * 8;
  float acc = 0.f;
#pragma unroll
  for (int j = 0; j < 8; j++) acc += p[j] * q[j];
  s[t] = acc;
}

// ---------------- aggregation layer 1 (online softmax, fused attn_dst) ----------------
__global__ __launch_bounds__(256) void agg1_kernel(
    const int* __restrict__ offs, const int* __restrict__ srcs,
    const float* __restrict__ s_src, const int* __restrict__ res,
    const float* __restrict__ ad, const float* __restrict__ hs1,
    const float* __restrict__ bias, float* __restrict__ h1, int n_dst) {
  int wid = (blockIdx.x * blockDim.x + threadIdx.x) >> 6;
  if (wid >= n_dst) return;
  int lane = threadIdx.x & 63;
  int h = lane >> 3;
  // fused attn_dst1: sd[h] = dot(hs1[res[wid], h*8:h*8+8], ad[h*8:h*8+8])
  int node = res[wid];
  float v = hs1[(size_t)node * 64 + lane] * ad[lane];
  v += __shfl_xor(v, 1);
  v += __shfl_xor(v, 2);
  v += __shfl_xor(v, 4);
  float sd = v;  // per-8-lane head group sum
  int beg = offs[wid], end = offs[wid + 1];
  float mx = -1e30f, den = 0.f, acc = 0.f;
  for (int i = beg; i < end; i += 8) {
    int m = end - i; if (m > 8) m = 8;
    int sr[8]; float ss[8], row[8];
#pragma unroll
    for (int j = 0; j < 8; j++) sr[j] = srcs[i + (j < m ? j : 0)];
#pragma unroll
    for (int j = 0; j < 8; j++) ss[j] = s_src[sr[j] * 8 + h];
#pragma unroll
    for (int j = 0; j < 8; j++) row[j] = hs1[(size_t)sr[j] * 64 + lane];
    float p[8];
#pragma unroll
    for (int j = 0; j < 8; j++) p[j] = (j < m) ? lrelu02(ss[j] + sd) : -1e30f;
    float bm = mx;
#pragma unroll
    for (int j = 0; j < 8; j++) bm = fmaxf(bm, p[j]);
    float scale = __expf(mx - bm);
    den *= scale;
    acc *= scale;
#pragma unroll
    for (int j = 0; j < 8; j++) {
      float w = __expf(p[j] - bm);
      den += w;
      acc += w * row[j];
    }
    mx = bm;
  }
  float val = (end > beg) ? acc / den : 0.f;
  val += bias[lane];
  val = val > 0.f ? val : __expf(val) - 1.f;  // ELU
  h1[(size_t)wid * 64 + lane] = val;
}

// ---------------- GEMM2 + s_src2: hs2 = h1 @ W2 (30000x64 @ 64x41) ----------------
__global__ __launch_bounds__(256) void gemm2_kernel(const float* __restrict__ h1,
                                                    const float* __restrict__ W2,
                                                    const float* __restrict__ a_src,
                                                    float* __restrict__ hs2,
                                                    float* __restrict__ ssrc, int M) {
  constexpr int C = 41;
  __shared__ float Ws[64 * C];
  for (int i = threadIdx.x; i < 64 * C; i += 256) Ws[i] = W2[i];
  __syncthreads();
  int lane = threadIdx.x & 63;
  int r = blockIdx.x * 4 + (threadIdx.x >> 6);
  if (r >= M) return;
  const float* row = h1 + (size_t)r * 64;
  float acc = 0.f;
  if (lane < C) {
#pragma unroll 8
    for (int k = 0; k < 64; k++) acc += row[k] * Ws[k * C + lane];
  }
  float t = (lane < C) ? acc * a_src[lane] : 0.f;
  t = wave_sum64(t);
  if (lane == 0) ssrc[r] = t;
  if (lane < C) hs2[(size_t)r * C + lane] = acc;
}

// ---------------- aggregation layer 2 (online softmax, fused attn_dst) + log_softmax ----
__global__ __launch_bounds__(256) void agg2_kernel(
    const int* __restrict__ offs, const int* __restrict__ srcs,
    const float* __restrict__ s_src, const int* __restrict__ res,
    const float* __restrict__ ad, const float* __restrict__ hs2,
    const float* __restrict__ bias, float* __restrict__ out, int n_dst) {
  constexpr int C = 41;
  int wid = (blockIdx.x * blockDim.x + threadIdx.x) >> 6;
  if (wid >= n_dst) return;
  int lane = threadIdx.x & 63;
  bool act = lane < C;
  // fused attn_dst2: sd = dot(hs2[res[wid]], ad)
  int node = res[wid];
  float dv = act ? hs2[(size_t)node * C + lane] * ad[lane] : 0.f;
  float sd = wave_sum64(dv);
  int beg = offs[wid], end = offs[wid + 1];
  float mx = -1e30f, den = 0.f, acc = 0.f;
  for (int i = beg; i < end; i += 8) {
    int m = end - i; if (m > 8) m = 8;
    int sr[8]; float ss[8], row[8];
#pragma unroll
    for (int j = 0; j < 8; j++) sr[j] = srcs[i + (j < m ? j : 0)];
#pragma unroll
    for (int j = 0; j < 8; j++) ss[j] = s_src[sr[j]];
#pragma unroll
    for (int j = 0; j < 8; j++) row[j] = act ? hs2[(size_t)sr[j] * C + lane] : 0.f;
    float p[8];
#pragma unroll
    for (int j = 0; j < 8; j++) p[j] = (j < m) ? lrelu02(ss[j] + sd) : -1e30f;
    float bm = mx;
#pragma unroll
    for (int j = 0; j < 8; j++) bm = fmaxf(bm, p[j]);
    float scale = __expf(mx - bm);
    den *= scale;
    acc *= scale;
#pragma unroll
    for (int j = 0; j < 8; j++) {
      float w = __expf(p[j] - bm);
      den += w;
      acc += w * row[j];
    }
    mx = bm;
  }
  float val = (end > beg) ? acc / den : 0.f;
  if (act) val += bias[lane];
  float lv = act ? val : -1e30f;
  float m2 = wave_max64(lv);
  float ex = act ? __expf(val - m2) : 0.f;
  float ssum = wave_sum64(ex);
  if (act) out[(size_t)wid * C + lane] = val - m2 - __logf(ssum);
}

// ---------------- launch ----------------
extern "C" void kernel_launch(void* const* d_in, const int* in_sizes, int n_in,
                              void* d_out, int out_size, void* d_ws, size_t ws_size,
                              hipStream_t stream) {
  const float* x    = (const float*)d_in[0];
  const int* n_id1  = (const int*)d_in[1];
  const int* res1   = (const int*)d_in[2];
  const int* esrc1  = (const int*)d_in[3];
  const int* edst1  = (const int*)d_in[4];
  const int* res2   = (const int*)d_in[5];
  const int* esrc2  = (const int*)d_in[6];
  const int* edst2  = (const int*)d_in[7];
  const float* W1   = (const float*)d_in[8];
  const float* as1  = (const float*)d_in[9];
  const float* ad1  = (const float*)d_in[10];
  const float* b1   = (const float*)d_in[11];
  const float* W2   = (const float*)d_in[12];
  const float* as2  = (const float*)d_in[13];
  const float* ad2  = (const float*)d_in[14];
  const float* b2   = (const float*)d_in[15];
  float* out = (float*)d_out;

  const int N1  = in_sizes[1];  // 120000
  const int N1D = in_sizes[2];  // 30000
  const int E1  = in_sizes[3];  // 960000
  const int N2D = in_sizes[5];  // 6000
  const int E2  = in_sizes[6];  // 192000
  const int NTOT = N1D + N2D;
  const int ETOT = E1 + E2;

  char* w = (char*)d_ws;
  size_t off = 0;
  auto alloc = [&](size_t bytes) -> void* {
    void* p = (void*)(w + off);
    off += (bytes + 255) & ~(size_t)255;
    return p;
  };
  float* hs1   = (float*)alloc((size_t)N1 * 64 * 4);
  float* ssrc1 = (float*)alloc((size_t)N1 * 8 * 4);
  float* h1    = (float*)alloc((size_t)N1D * 64 * 4);
  float* hs2   = (float*)alloc((size_t)N1D * 41 * 4);
  float* ssrc2 = (float*)alloc((size_t)N1D * 4);
  // counts+cursor in ONE contiguous alloc: the single memset below must cover
  // both exactly (round-2 bug: separate 256-aligned allocs left a 128 B
  // poisoned gap inside cursor -> wild writes -> GPU abort).
  int* counts  = (int*)alloc((size_t)2 * NTOT * 4);
  int* cursor  = counts + NTOT;
  int* offs    = (int*)alloc((size_t)(NTOT + 1) * 4);
  int* bsum    = (int*)alloc((size_t)256 * 4);
  int* epay    = (int*)alloc((size_t)ETOT * 4);
  short* Wp    = (short*)alloc((size_t)19 * 4 * 64 * 8 * 2);
  (void)ws_size; (void)n_in; (void)out_size;

  hipMemsetAsync(counts, 0, (size_t)2 * NTOT * 4, stream);  // counts + cursor exactly

  // CSR build (hist fused with W1 prepack), scan, payload scatter
  const int nbE = (ETOT + 255) / 256;
  const int nb = (NTOT + 255) / 256;  // 141
  hist_prepack_kernel<<<nbE + 19, 256, 0, stream>>>(edst1, edst2, counts, W1, Wp, E1, E2, N1D, nbE);
  scan1_kernel<<<nb, 256, 0, stream>>>(counts, offs, bsum, NTOT);
  scan2_kernel<<<1, 256, 0, stream>>>(bsum, nb);
  scan3_kernel<<<nb, 256, 0, stream>>>(offs, bsum, NTOT, ETOT);
  scatter_kernel<<<nbE, 256, 0, stream>>>(edst1, esrc1, edst2, esrc2, offs, cursor, epay, E1, E2, N1D);

  // layer 1
  gemm1_mfma_kernel<<<(N1 + 63) / 64, 256, 0, stream>>>(x, n_id1, Wp, hs1, N1);
  attn_src1_kernel<<<(N1 * 8 + 255) / 256, 256, 0, stream>>>(hs1, as1, ssrc1, N1);
  agg1_kernel<<<(N1D + 3) / 4, 256, 0, stream>>>(offs, epay, ssrc1, res1, ad1, hs1, b1, h1, N1D);

  // layer 2 (CSR segment 2 lives at offs + N1D, payload is layer-2 src node id)
  gemm2_kernel<<<(N1D + 3) / 4, 256, 0, stream>>>(h1, W2, as2, hs2, ssrc2, N1D);
  agg2_kernel<<<(N2D + 3) / 4, 256, 0, stream>>>(offs + N1D, epay, ssrc2, res2, ad2, hs2, b2, out, N2D);
}